// Round 5
// baseline (1217.296 us; speedup 1.0000x reference)
//
#include <hip/hip_runtime.h>
#include <hip/hip_fp16.h>
#include <math.h>

#define DIM 4096
#define RDIM 16
#define RIDGE 1e-5f
#define NPKP 144    // padded pair count (9 MFMA tiles of 16)
#define KCH 8       // K-chunks for MFMA buildA
#define KT 128      // k-tile staged in LDS per buildA inner iteration
#define NSL 128     // tpart slices (it_c row-slices of 32)
#define SROWS 32    // rows per it_c block
#define NSLA 128    // psi2 slices (it_a row-slices of 32)
#define SROWSA 32   // rows per it_a block

typedef __attribute__((ext_vector_type(8))) short bf16x8;
typedef __attribute__((ext_vector_type(4))) float f32x4;

__device__ __forceinline__ int pidx(int r, int s) { return r * (31 - r) / 2 + s; } // r<=s

__device__ __forceinline__ float alpha_of(float cl) {
    return cl * (1.f - erff(sqrtf(cl))) +
           0.5f * (erff(cl * 0.70710678118f) -
                   0.79788456080f * cl * expf(-0.5f * cl * cl));
}

__device__ __forceinline__ unsigned short bf16_rne(float p) {
    unsigned bits = __float_as_uint(p);
    return (unsigned short)((bits + 0x7FFFu + ((bits >> 16) & 1u)) >> 16);
}

// half-pair u32 -> bf16 0/1 mask pair u32 (nonzero-magnitude test per half)
__device__ __forceinline__ unsigned mask2_of(unsigned w) {
    return ((w & 0x00007FFFu) ? 0x00003F80u : 0u) |
           ((w & 0x7FFF0000u) ? 0x3F800000u : 0u);
}

// ------- transpose: X(fp32) -> Xh (fp16, row-major) + XhT (fp16, transposed)
// fused per-column and per-row observed counts.
__global__ void __launch_bounds__(256) k_transpose(const float* __restrict__ X,
                                                   __half* __restrict__ Xh,
                                                   __half* __restrict__ XhT,
                                                   float* __restrict__ cntc,
                                                   float* __restrict__ cntr) {
    __shared__ float tile[64][65];
    __shared__ float redc[4][64];
    __shared__ float redr[4][64];
    int bx = blockIdx.x, by = blockIdx.y;
    int lx = threadIdx.x & 63;
    int ly = threadIdx.x >> 6;
    float ccnt = 0.f;
#pragma unroll
    for (int i = 0; i < 16; ++i) {
        int r = ly + i * 4;
        float v = X[(size_t)(by * 64 + r) * DIM + bx * 64 + lx];
        tile[r][lx] = v;
        Xh[(size_t)(by * 64 + r) * DIM + bx * 64 + lx] = __float2half(v);
        ccnt += (v != 0.f) ? 1.f : 0.f;
    }
    redc[ly][lx] = ccnt;
    __syncthreads();
#pragma unroll
    for (int i = 0; i < 16; ++i) {
        int r = ly + i * 4;
        XhT[(size_t)(bx * 64 + r) * DIM + by * 64 + lx] = __float2half(tile[lx][r]);
    }
    float rcnt = 0.f;
#pragma unroll
    for (int j = 0; j < 16; ++j)
        rcnt += (tile[lx][ly * 16 + j] != 0.f) ? 1.f : 0.f;
    redr[ly][lx] = rcnt;
    __syncthreads();
    if (threadIdx.x < 64) {
        int c = threadIdx.x;
        atomicAdd(&cntc[bx * 64 + c],
                  redc[0][c] + redc[1][c] + redc[2][c] + redc[3][c]);
    } else if (threadIdx.x < 128) {
        int r = threadIdx.x - 64;
        atomicAdd(&cntr[by * 64 + r],
                  redr[0][r] + redr[1][r] + redr[2][r] + redr[3][r]);
    }
}

// ---------------- init copies ----------------------------------------------
__global__ void k_init_uc(const float* __restrict__ U, float* __restrict__ Uc) {
    int i = blockIdx.x * 256 + threadIdx.x;
    ((float4*)Uc)[i] = ((const float4*)U)[i];
}
__global__ void k_init_vt(const float* __restrict__ V, float* __restrict__ Vtb) {
    int n = blockIdx.x * 256 + threadIdx.x;
#pragma unroll
    for (int r = 0; r < RDIM; ++r) Vtb[(size_t)n * RDIM + r] = V[(size_t)r * DIM + n];
}

// ---------------- Pt[rs][m] = bf16(D[m][r] * D[m][s]), pidx order ----------
// Only used ONCE (layer-0 V step); later Pt builds fused into it_d.
__global__ void __launch_bounds__(256) k_prep(const float* __restrict__ D,
                                              unsigned short* __restrict__ Pt) {
    int rs = blockIdx.y;
    int rr = 16, ss = 0;
#pragma unroll
    for (int r = 0; r < 16; ++r) {
        int base = r * (31 - r) / 2;
        if (rs >= base + r && rs <= base + 15) { rr = r; ss = rs - base; }
    }
    int m = blockIdx.x * 256 + threadIdx.x;
    float p = 0.f;
    if (rr < 16) p = D[(size_t)m * RDIM + rr] * D[(size_t)m * RDIM + ss];
    Pt[(size_t)rs * DIM + m] = bf16_rne(p);
}

// ---------------- MFMA buildA, KT=128, 16B staging loads -------------------
// grid 512: (bid&63) = c-block of 64, (bid>>6) = k-chunk (0..7, 512 k each).
__global__ void __launch_bounds__(256) k_buildA(const __half* __restrict__ XphT,
                                                const unsigned short* __restrict__ Pt,
                                                float* __restrict__ Apad) {
    __shared__ unsigned short wtile[64][KT + 8];    // 64 x 136 bf16 (272B rows, 16-aligned)
    __shared__ unsigned short ptile[144][KT + 8];   // 144 x 136 bf16
    const int tid = threadIdx.x;
    const int wave = tid >> 6;
    const int lane = tid & 63;
    const int n = lane & 15;
    const int quad = lane >> 4;
    const int c0 = (blockIdx.x & 63) * 64;
    const int kch = blockIdx.x >> 6;            // 0..7
    const int kbase0 = kch * (DIM / KCH);       // *512

    f32x4 acc[9];
#pragma unroll
    for (int t = 0; t < 9; ++t) acc[t] = (f32x4){0.f, 0.f, 0.f, 0.f};

    for (int kt = 0; kt < (DIM / KCH) / KT; ++kt) {   // 4 iterations
        const int kb = kbase0 + kt * KT;
        __syncthreads();
        // stage W mask from fp16: 64 rows x 128 halves = 1024 16B-chunks = 256 thr x 4
#pragma unroll
        for (int j = 0; j < 4; ++j) {
            int idx = j * 256 + tid;
            int r = idx >> 4;
            int ccol = (idx & 15) * 8;
            uint4 v = *(const uint4*)(XphT + (size_t)(c0 + r) * DIM + kb + ccol);
            uint4 mk;
            mk.x = mask2_of(v.x);
            mk.y = mask2_of(v.y);
            mk.z = mask2_of(v.z);
            mk.w = mask2_of(v.w);
            *(uint4*)&wtile[r][ccol] = mk;
        }
        // stage Pt: 144 rows x 128 bf16 = 2304 16B-chunks = 256 thr x 9
#pragma unroll
        for (int j = 0; j < 9; ++j) {
            int idx = j * 256 + tid;
            int pr = idx >> 4;
            int pc = (idx & 15) * 8;
            *(uint4*)&ptile[pr][pc] = *(const uint4*)(Pt + (size_t)pr * DIM + kb + pc);
        }
        __syncthreads();
        // MFMA over the staged tile
#pragma unroll
        for (int inner = 0; inner < 4; ++inner) {
            bf16x8 bfrag = *(const bf16x8*)&wtile[wave * 16 + n][inner * 32 + quad * 8];
#pragma unroll
            for (int t = 0; t < 9; ++t) {
                bf16x8 afrag = *(const bf16x8*)&ptile[t * 16 + n][inner * 32 + quad * 8];
                acc[t] = __builtin_amdgcn_mfma_f32_16x16x32_bf16(afrag, bfrag, acc[t], 0, 0, 0);
            }
        }
    }
    // C/D layout: col = lane&15 (c), row = quad*4 + reg (rs within tile)
    const int c = c0 + wave * 16 + n;
    float* dst0 = Apad + ((size_t)kch * DIM + c) * NPKP + quad * 4;
#pragma unroll
    for (int t = 0; t < 9; ++t)
        *(float4*)(dst0 + t * 16) = (float4){acc[t].x, acc[t].y, acc[t].z, acc[t].w};
}

// ------- invert 16x16 SPD; chunk reduction fused; zeros snum[0..1] ---------
// grid 1024 x 64 thr: 4 matrices/block.
__global__ void __launch_bounds__(64) k_invert(const float* __restrict__ Apad,
                                               float* __restrict__ Ainv,
                                               float* __restrict__ snum) {
    const int tid = threadIdx.x;
    int c = blockIdx.x * 4 + (tid >> 4);
    int j = tid & 15;
    if (j == 0) { snum[c] = 0.f; snum[c + DIM] = 0.f; }

    float a[16], b[16];
#pragma unroll
    for (int s = 0; s < 16; ++s) {
        int r0 = j < s ? j : s;
        int s0 = j < s ? s : j;
        int off = pidx(r0, s0);
        float acc = 0.f;
#pragma unroll
        for (int ch = 0; ch < KCH; ++ch)
            acc += Apad[((size_t)ch * DIM + c) * NPKP + off];
        a[s] = acc;
        b[s] = 0.f;
    }
    a[j] += RIDGE;
    b[j] = 1.f;

#pragma unroll
    for (int k = 0; k < RDIM; ++k) {
        float pivA[16], pivB[16];
#pragma unroll
        for (int s = 0; s < 16; ++s) {
            pivA[s] = __shfl(a[s], k, 16);
            pivB[s] = __shfl(b[s], k, 16);
        }
        float pinv = 1.f / pivA[k];
        float f = a[k];
        if (j == k) {
#pragma unroll
            for (int s = 0; s < 16; ++s) { a[s] = pivA[s] * pinv; b[s] = pivB[s] * pinv; }
        } else {
#pragma unroll
            for (int s = 0; s < 16; ++s) {
                a[s] -= f * pinv * pivA[s];
                b[s] -= f * pinv * pivB[s];
            }
        }
    }
#pragma unroll
    for (int s = 0; s < 16; ++s) Ainv[(size_t)c * 256 + j * 16 + s] = b[s];
}

// ---------------- pass 1: psi^2 partials -> atomic snum_wr -----------------
// grid (4, NSLA): 4 cols/thread (ushort4 8B X loads), 32-row slices.
__global__ void __launch_bounds__(256) k_it_a(const __half* __restrict__ Xph,
                                              const float* __restrict__ D,
                                              const float* __restrict__ B,
                                              const float* __restrict__ snum_rd,
                                              const float* __restrict__ sigma,
                                              const float* __restrict__ cnt,
                                              const float* __restrict__ cvec,
                                              const float* __restrict__ lvec,
                                              int layer, int use_s0,
                                              float* __restrict__ snum_wr) {
    __shared__ float ds[SROWSA * RDIM];  // 2 KB
    const int tid = threadIdx.x;
    const int c = blockIdx.x * 1024 + tid * 4;
    const int m0 = blockIdx.y * SROWSA;
    if (tid < SROWSA * RDIM / 4)
        ((float4*)ds)[tid] = ((const float4*)(D + (size_t)m0 * RDIM))[tid];

    float cl = cvec[layer];
    float invsg[4];
    if (use_s0) {
        float is0 = 1.f / sigma[0];
#pragma unroll
        for (int i = 0; i < 4; ++i) invsg[i] = is0;
    } else {
        float ll = lvec[layer];
        float al = alpha_of(cl);
#pragma unroll
        for (int i = 0; i < 4; ++i)
            invsg[i] = 1.f / (ll * sqrtf(snum_rd[c + i]) * rsqrtf(2.f * cnt[c + i] * al));
    }
    float beta[4][16];
#pragma unroll
    for (int i = 0; i < 4; ++i)
#pragma unroll
        for (int q = 0; q < 4; ++q) {
            float4 t4 = ((const float4*)(B + (size_t)(c + i) * RDIM))[q];
            beta[i][q * 4 + 0] = t4.x; beta[i][q * 4 + 1] = t4.y;
            beta[i][q * 4 + 2] = t4.z; beta[i][q * 4 + 3] = t4.w;
        }
    __syncthreads();

    float acc[4] = {0.f, 0.f, 0.f, 0.f};
#pragma unroll 4
    for (int m = 0; m < SROWSA; ++m) {
        float u[16];
#pragma unroll
        for (int q = 0; q < 4; ++q) {
            float4 u4 = ((const float4*)(ds + m * RDIM))[q];
            u[q * 4 + 0] = u4.x; u[q * 4 + 1] = u4.y;
            u[q * 4 + 2] = u4.z; u[q * 4 + 3] = u4.w;
        }
        ushort4 h4 = *(const ushort4*)(Xph + (size_t)(m0 + m) * DIM + c);
        float2 xlo = __half22float2(*(const __half2*)&h4.x);
        float2 xhi = __half22float2(*(const __half2*)&h4.z);
        float xv[4] = {xlo.x, xlo.y, xhi.x, xhi.y};
#pragma unroll
        for (int i = 0; i < 4; ++i) {
            float dot = 0.f;
#pragma unroll
            for (int s = 0; s < 16; ++s) dot += u[s] * beta[i][s];
            float res = (xv[i] != 0.f) ? (xv[i] - dot) : 0.f;
            float psi = fminf(fmaxf(res * invsg[i], -cl), cl);
            acc[i] += psi * psi;
        }
    }
#pragma unroll
    for (int i = 0; i < 4; ++i) atomicAdd(&snum_wr[c + i], acc[i]);
}

// ---------------- pass 2: t slice partials, sig computed inline ------------
// grid (4, NSL): 4 cols/thread (ushort4 8B X loads), 32-row slices.
__global__ void __launch_bounds__(256) k_it_c(const __half* __restrict__ Xph,
                                              const float* __restrict__ D,
                                              const float* __restrict__ B,
                                              const float* __restrict__ snum_rd,
                                              const float* __restrict__ cnt,
                                              const float* __restrict__ cvec,
                                              const float* __restrict__ lvec,
                                              int layer,
                                              float* __restrict__ tpart) {
    __shared__ float ds[SROWS * RDIM];  // 2 KB
    const int tid = threadIdx.x;
    const int c = blockIdx.x * 1024 + tid * 4;
    const int m0 = blockIdx.y * SROWS;
    if (tid < SROWS * RDIM / 4)
        ((float4*)ds)[tid] = ((const float4*)(D + (size_t)m0 * RDIM))[tid];

    float cl = cvec[layer];
    float ll = lvec[layer];
    float al = alpha_of(cl);
    float sg[4], invsg[4];
#pragma unroll
    for (int i = 0; i < 4; ++i) {
        sg[i] = ll * sqrtf(snum_rd[c + i]) * rsqrtf(2.f * cnt[c + i] * al);
        invsg[i] = 1.f / sg[i];
    }
    float beta[4][16];
#pragma unroll
    for (int i = 0; i < 4; ++i)
#pragma unroll
        for (int q = 0; q < 4; ++q) {
            float4 t4 = ((const float4*)(B + (size_t)(c + i) * RDIM))[q];
            beta[i][q * 4 + 0] = t4.x; beta[i][q * 4 + 1] = t4.y;
            beta[i][q * 4 + 2] = t4.z; beta[i][q * 4 + 3] = t4.w;
        }
    __syncthreads();

    float tac[4][16];
#pragma unroll
    for (int i = 0; i < 4; ++i)
#pragma unroll
        for (int s = 0; s < 16; ++s) tac[i][s] = 0.f;

#pragma unroll 2
    for (int m = 0; m < SROWS; ++m) {
        float u[16];
#pragma unroll
        for (int q = 0; q < 4; ++q) {
            float4 u4 = ((const float4*)(ds + m * RDIM))[q];
            u[q * 4 + 0] = u4.x; u[q * 4 + 1] = u4.y;
            u[q * 4 + 2] = u4.z; u[q * 4 + 3] = u4.w;
        }
        ushort4 h4 = *(const ushort4*)(Xph + (size_t)(m0 + m) * DIM + c);
        float2 xlo = __half22float2(*(const __half2*)&h4.x);
        float2 xhi = __half22float2(*(const __half2*)&h4.z);
        float xv[4] = {xlo.x, xlo.y, xhi.x, xhi.y};
#pragma unroll
        for (int i = 0; i < 4; ++i) {
            float dot = 0.f;
#pragma unroll
            for (int s = 0; s < 16; ++s) dot += u[s] * beta[i][s];
            float res = (xv[i] != 0.f) ? (xv[i] - dot) : 0.f;
            float psi2 = fminf(fmaxf(res * invsg[i], -cl), cl);
            float coeff = psi2 * sg[i];
#pragma unroll
            for (int s = 0; s < 16; ++s) tac[i][s] += u[s] * coeff;
        }
    }
    float* tsl = tpart + (size_t)blockIdx.y * DIM * RDIM;
#pragma unroll
    for (int i = 0; i < 4; ++i)
#pragma unroll
        for (int q = 0; q < 4; ++q)
            *(float4*)(tsl + (size_t)(c + i) * RDIM + q * 4) =
                make_float4(tac[i][q * 4 + 0], tac[i][q * 4 + 1],
                            tac[i][q * 4 + 2], tac[i][q * 4 + 3]);
}

// ------- beta update: B += mu * Ainv @ (sum of tpart slices) ---------------
// grid 256 x 256 thr: 16 cols/block, all threads active; optional Pt build.
__global__ void __launch_bounds__(256) k_it_d(const float* __restrict__ Ainv,
                                              const float* __restrict__ tpart,
                                              const float* __restrict__ mvec, int layer,
                                              float* __restrict__ B,
                                              unsigned short* __restrict__ Pt, int do_pt) {
    __shared__ float t_sh[16][16];
    __shared__ unsigned char prr[144], pss[144];
    const int tid = threadIdx.x;
    if (do_pt && tid < 144) {
        int rs = tid;
        int rr = 255, ss = 0;
#pragma unroll
        for (int r = 0; r < 16; ++r) {
            int base = r * (31 - r) / 2;
            if (rs >= base + r && rs <= base + 15) { rr = r; ss = rs - base; }
        }
        prr[rs] = (unsigned char)rr;
        pss[rs] = (unsigned char)ss;
    }
    const int c0 = blockIdx.x * 16;
    const int cl_ = tid >> 4;
    const int j = tid & 15;
    float tv = 0.f;
#pragma unroll 8
    for (int sl = 0; sl < NSL; ++sl)
        tv += tpart[((size_t)sl * DIM + c0 + cl_) * RDIM + j];
    t_sh[cl_][j] = tv;
    __syncthreads();

    int c = c0 + cl_;
    float ml = mvec[layer];
    float d = 0.f;
#pragma unroll
    for (int q = 0; q < 4; ++q) {
        float4 a4 = *(const float4*)(Ainv + (size_t)c * 256 + j * 16 + q * 4);
        d += a4.x * t_sh[cl_][q * 4 + 0] + a4.y * t_sh[cl_][q * 4 + 1] +
             a4.z * t_sh[cl_][q * 4 + 2] + a4.w * t_sh[cl_][q * 4 + 3];
    }
    float bnew = B[(size_t)c * RDIM + j] + ml * d;
    B[(size_t)c * RDIM + j] = bnew;

    if (do_pt) {
        int gbase = tid & 48;   // 16-lane group base within wave
#pragma unroll
        for (int t = 0; t < 9; ++t) {
            int rs = t * 16 + j;
            int rr = prr[rs], ss2 = pss[rs];
            float brr = __shfl(bnew, gbase + (rr & 15), 64);
            float bss = __shfl(bnew, gbase + (ss2 & 15), 64);
            float p = (rr < 16) ? brr * bss : 0.f;
            Pt[(size_t)rs * DIM + c] = bf16_rne(p);
        }
    }
}

// ---------------- final out = Uc @ Vtb^T -----------------------------------
__global__ void __launch_bounds__(256) k_out(const float* __restrict__ Uc,
                                             const float* __restrict__ Vtb,
                                             float* __restrict__ out) {
    __shared__ float us[64 * RDIM];
    int j = blockIdx.x * 256 + threadIdx.x;
    int i0 = blockIdx.y * 64;
    ((float4*)us)[threadIdx.x] = ((const float4*)(Uc + (size_t)i0 * RDIM))[threadIdx.x];
    float beta[16];
#pragma unroll
    for (int q = 0; q < 4; ++q) {
        float4 t4 = ((const float4*)(Vtb + (size_t)j * RDIM))[q];
        beta[q * 4 + 0] = t4.x; beta[q * 4 + 1] = t4.y;
        beta[q * 4 + 2] = t4.z; beta[q * 4 + 3] = t4.w;
    }
    __syncthreads();
#pragma unroll 4
    for (int r = 0; r < 64; ++r) {
        float dot = 0.f;
#pragma unroll
        for (int q = 0; q < 4; ++q) {
            float4 u4 = *(const float4*)(us + r * RDIM + q * 4);
            dot += u4.x * beta[q * 4 + 0] + u4.y * beta[q * 4 + 1] +
                   u4.z * beta[q * 4 + 2] + u4.w * beta[q * 4 + 3];
        }
        out[(size_t)(i0 + r) * DIM + j] = dot;
    }
}

extern "C" void kernel_launch(void* const* d_in, const int* in_sizes, int n_in,
                              void* d_out, int out_size, void* d_ws, size_t ws_size,
                              hipStream_t stream) {
    const float* U = (const float*)d_in[0];
    const float* V = (const float*)d_in[1];
    const float* X = (const float*)d_in[2];
    const float* cvec = (const float*)d_in[3];
    const float* lvec = (const float*)d_in[4];
    const float* mvec = (const float*)d_in[5];
    const float* sigma = (const float*)d_in[6];
    float* out = (float*)d_out;

    float* ws = (float*)d_ws;
    // BIG aliased region: Apad (buildA..invert) vs tpart (iteration phases).
    // Apad = KCH*4096*144 = 4,718,592 f; tpart = 128*4096*16 = 8,388,608 f.
    float* big    = ws;
    float* Apad   = big;
    float* tpart  = big;
    float* endbig = big + (size_t)NSL * DIM * RDIM;
    float* Ainv   = endbig;                       // 4096*256
    float* snum   = Ainv + (size_t)DIM * 256;     // 2*4096 (ping-pong psi2 sums)
    float* cntc   = snum + 2 * DIM;               // 4096
    float* cntr   = cntc + DIM;                   // 4096
    float* Uc     = cntr + DIM;                   // 4096*16
    float* Vtb    = Uc + (size_t)DIM * RDIM;      // 4096*16
    unsigned short* Pt = (unsigned short*)(Vtb + (size_t)DIM * RDIM); // 144*4096 u16
    // fp16 X copies live in d_out (scratch until k_out): 2 * 16.7M halves = out_size.
    __half* Xh  = (__half*)out;                   // row-major fp16 X
    __half* XhT = Xh + (size_t)DIM * DIM;         // transposed fp16 X

    // zero the atomic count targets (cntc, cntr — contiguous)
    hipMemsetAsync(cntc, 0, (size_t)2 * DIM * sizeof(float), stream);

    k_transpose<<<dim3(64, 64), 256, 0, stream>>>(X, Xh, XhT, cntc, cntr);
    k_init_uc<<<64, 256, 0, stream>>>(U, Uc);
    k_init_vt<<<16, 256, 0, stream>>>(V, Vtb);
    // only Pt build not fused into an it_d: layer-0 V step from initial Uc
    k_prep<<<dim3(16, NPKP), 256, 0, stream>>>(Uc, Pt);

    for (int layer = 0; layer < 3; ++layer) {
        int last = (layer == 2);
        // ---- V step: design Uc, beta Vtb; mask rows from XhT, iter rows from Xh
        k_buildA<<<512, 256, 0, stream>>>(XhT, Pt, Apad);
        k_invert<<<1024, 64, 0, stream>>>(Apad, Ainv, snum);   // zeros snum[0..1]
        k_it_a<<<dim3(4, NSLA), 256, 0, stream>>>(Xh, Uc, Vtb, snum, sigma, cntc,
                                                  cvec, lvec, layer, 1, snum);
        k_it_c<<<dim3(4, NSL), 256, 0, stream>>>(Xh, Uc, Vtb, snum, cntc,
                                                 cvec, lvec, layer, tpart);
        k_it_d<<<256, 256, 0, stream>>>(Ainv, tpart, mvec, layer, Vtb, nullptr, 0);
        k_it_a<<<dim3(4, NSLA), 256, 0, stream>>>(Xh, Uc, Vtb, snum, sigma, cntc,
                                                  cvec, lvec, layer, 0, snum + DIM);
        k_it_c<<<dim3(4, NSL), 256, 0, stream>>>(Xh, Uc, Vtb, snum + DIM, cntc,
                                                 cvec, lvec, layer, tpart);
        k_it_d<<<256, 256, 0, stream>>>(Ainv, tpart, mvec, layer, Vtb, Pt, 1);

        // ---- U step: design Vtb, beta Uc; mask rows from Xh, iter rows from XhT
        k_buildA<<<512, 256, 0, stream>>>(Xh, Pt, Apad);
        k_invert<<<1024, 64, 0, stream>>>(Apad, Ainv, snum);   // zeros snum[0..1]
        k_it_a<<<dim3(4, NSLA), 256, 0, stream>>>(XhT, Vtb, Uc, snum, sigma, cntr,
                                                  cvec, lvec, layer, 1, snum);
        k_it_c<<<dim3(4, NSL), 256, 0, stream>>>(XhT, Vtb, Uc, snum, cntr,
                                                 cvec, lvec, layer, tpart);
        k_it_d<<<256, 256, 0, stream>>>(Ainv, tpart, mvec, layer, Uc, nullptr, 0);
        k_it_a<<<dim3(4, NSLA), 256, 0, stream>>>(XhT, Vtb, Uc, snum, sigma, cntr,
                                                  cvec, lvec, layer, 0, snum + DIM);
        k_it_c<<<dim3(4, NSL), 256, 0, stream>>>(XhT, Vtb, Uc, snum + DIM, cntr,
                                                 cvec, lvec, layer, tpart);
        k_it_d<<<256, 256, 0, stream>>>(Ainv, tpart, mvec, layer, Uc,
                                        last ? nullptr : Pt, last ? 0 : 1);
    }
    k_out<<<dim3(16, 64), 256, 0, stream>>>(Uc, Vtb, out);
}

// Round 6
// 1147.685 us; speedup vs baseline: 1.0607x; 1.0607x over previous
//
#include <hip/hip_runtime.h>
#include <hip/hip_fp16.h>
#include <math.h>

#define DIM 4096
#define RDIM 16
#define RIDGE 1e-5f
#define NPKP 144    // padded pair count (9 MFMA tiles of 16)
#define KCH 8       // K-chunks for MFMA buildA
#define KT 128      // k-tile staged in LDS per buildA inner iteration
#define NC 8        // columns owned per k_hub block

typedef __attribute__((ext_vector_type(8))) short bf16x8;
typedef __attribute__((ext_vector_type(4))) float f32x4;

__device__ __forceinline__ int pidx(int r, int s) { return r * (31 - r) / 2 + s; } // r<=s

__device__ __forceinline__ float alpha_of(float cl) {
    return cl * (1.f - erff(sqrtf(cl))) +
           0.5f * (erff(cl * 0.70710678118f) -
                   0.79788456080f * cl * expf(-0.5f * cl * cl));
}

__device__ __forceinline__ unsigned short bf16_rne(float p) {
    unsigned bits = __float_as_uint(p);
    return (unsigned short)((bits + 0x7FFFu + ((bits >> 16) & 1u)) >> 16);
}

// half-pair u32 -> bf16 0/1 mask pair u32 (nonzero-magnitude test per half)
__device__ __forceinline__ unsigned mask2_of(unsigned w) {
    return ((w & 0x00007FFFu) ? 0x00003F80u : 0u) |
           ((w & 0x7FFF0000u) ? 0x3F800000u : 0u);
}

// ------- transpose: X(fp32) -> Xh (fp16, row-major) + XhT (fp16, transposed)
// fused per-column and per-row observed counts.
__global__ void __launch_bounds__(256) k_transpose(const float* __restrict__ X,
                                                   __half* __restrict__ Xh,
                                                   __half* __restrict__ XhT,
                                                   float* __restrict__ cntc,
                                                   float* __restrict__ cntr) {
    __shared__ float tile[64][65];
    __shared__ float redc[4][64];
    __shared__ float redr[4][64];
    int bx = blockIdx.x, by = blockIdx.y;
    int lx = threadIdx.x & 63;
    int ly = threadIdx.x >> 6;
    float ccnt = 0.f;
#pragma unroll
    for (int i = 0; i < 16; ++i) {
        int r = ly + i * 4;
        float v = X[(size_t)(by * 64 + r) * DIM + bx * 64 + lx];
        tile[r][lx] = v;
        Xh[(size_t)(by * 64 + r) * DIM + bx * 64 + lx] = __float2half(v);
        ccnt += (v != 0.f) ? 1.f : 0.f;
    }
    redc[ly][lx] = ccnt;
    __syncthreads();
#pragma unroll
    for (int i = 0; i < 16; ++i) {
        int r = ly + i * 4;
        XhT[(size_t)(bx * 64 + r) * DIM + by * 64 + lx] = __float2half(tile[lx][r]);
    }
    float rcnt = 0.f;
#pragma unroll
    for (int j = 0; j < 16; ++j)
        rcnt += (tile[lx][ly * 16 + j] != 0.f) ? 1.f : 0.f;
    redr[ly][lx] = rcnt;
    __syncthreads();
    if (threadIdx.x < 64) {
        int c = threadIdx.x;
        atomicAdd(&cntc[bx * 64 + c],
                  redc[0][c] + redc[1][c] + redc[2][c] + redc[3][c]);
    } else if (threadIdx.x < 128) {
        int r = threadIdx.x - 64;
        atomicAdd(&cntr[by * 64 + r],
                  redr[0][r] + redr[1][r] + redr[2][r] + redr[3][r]);
    }
}

// ---------------- init copies ----------------------------------------------
__global__ void k_init_uc(const float* __restrict__ U, float* __restrict__ Uc,
                          __half* __restrict__ Uch) {
    int i = blockIdx.x * 256 + threadIdx.x;
    float4 v = ((const float4*)U)[i];
    ((float4*)Uc)[i] = v;
    __half2 h0 = __floats2half2_rn(v.x, v.y);
    __half2 h1 = __floats2half2_rn(v.z, v.w);
    *(__half2*)(Uch + (size_t)i * 4)     = h0;
    *(__half2*)(Uch + (size_t)i * 4 + 2) = h1;
}
__global__ void k_init_vt(const float* __restrict__ V, float* __restrict__ Vtb) {
    int n = blockIdx.x * 256 + threadIdx.x;
#pragma unroll
    for (int r = 0; r < RDIM; ++r) Vtb[(size_t)n * RDIM + r] = V[(size_t)r * DIM + n];
}

// ---------------- Pt[rs][m] = bf16(D[m][r] * D[m][s]), pidx order ----------
// Only used ONCE (layer-0 V step); later Pt builds fused into k_hub epilogue.
__global__ void __launch_bounds__(256) k_prep(const float* __restrict__ D,
                                              unsigned short* __restrict__ Pt) {
    int rs = blockIdx.y;
    int rr = 16, ss = 0;
#pragma unroll
    for (int r = 0; r < 16; ++r) {
        int base = r * (31 - r) / 2;
        if (rs >= base + r && rs <= base + 15) { rr = r; ss = rs - base; }
    }
    int m = blockIdx.x * 256 + threadIdx.x;
    float p = 0.f;
    if (rr < 16) p = D[(size_t)m * RDIM + rr] * D[(size_t)m * RDIM + ss];
    Pt[(size_t)rs * DIM + m] = bf16_rne(p);
}

// ---------------- MFMA buildA, KT=128, 16B staging loads -------------------
// grid 512: (bid&63) = c-block of 64, (bid>>6) = k-chunk (0..7, 512 k each).
__global__ void __launch_bounds__(256) k_buildA(const __half* __restrict__ XphT,
                                                const unsigned short* __restrict__ Pt,
                                                float* __restrict__ Apad) {
    __shared__ unsigned short wtile[64][KT + 8];
    __shared__ unsigned short ptile[144][KT + 8];
    const int tid = threadIdx.x;
    const int wave = tid >> 6;
    const int lane = tid & 63;
    const int n = lane & 15;
    const int quad = lane >> 4;
    const int c0 = (blockIdx.x & 63) * 64;
    const int kch = blockIdx.x >> 6;
    const int kbase0 = kch * (DIM / KCH);

    f32x4 acc[9];
#pragma unroll
    for (int t = 0; t < 9; ++t) acc[t] = (f32x4){0.f, 0.f, 0.f, 0.f};

    for (int kt = 0; kt < (DIM / KCH) / KT; ++kt) {   // 4 iterations
        const int kb = kbase0 + kt * KT;
        __syncthreads();
#pragma unroll
        for (int j = 0; j < 4; ++j) {
            int idx = j * 256 + tid;
            int r = idx >> 4;
            int ccol = (idx & 15) * 8;
            uint4 v = *(const uint4*)(XphT + (size_t)(c0 + r) * DIM + kb + ccol);
            uint4 mk;
            mk.x = mask2_of(v.x);
            mk.y = mask2_of(v.y);
            mk.z = mask2_of(v.z);
            mk.w = mask2_of(v.w);
            *(uint4*)&wtile[r][ccol] = mk;
        }
#pragma unroll
        for (int j = 0; j < 9; ++j) {
            int idx = j * 256 + tid;
            int pr = idx >> 4;
            int pc = (idx & 15) * 8;
            *(uint4*)&ptile[pr][pc] = *(const uint4*)(Pt + (size_t)pr * DIM + kb + pc);
        }
        __syncthreads();
#pragma unroll
        for (int inner = 0; inner < 4; ++inner) {
            bf16x8 bfrag = *(const bf16x8*)&wtile[wave * 16 + n][inner * 32 + quad * 8];
#pragma unroll
            for (int t = 0; t < 9; ++t) {
                bf16x8 afrag = *(const bf16x8*)&ptile[t * 16 + n][inner * 32 + quad * 8];
                acc[t] = __builtin_amdgcn_mfma_f32_16x16x32_bf16(afrag, bfrag, acc[t], 0, 0, 0);
            }
        }
    }
    const int c = c0 + wave * 16 + n;
    float* dst0 = Apad + ((size_t)kch * DIM + c) * NPKP + quad * 4;
#pragma unroll
    for (int t = 0; t < 9; ++t)
        *(float4*)(dst0 + t * 16) = (float4){acc[t].x, acc[t].y, acc[t].z, acc[t].w};
}

// =================== fused per-column hubreg solver ========================
// grid 512 blocks x 256 thr. Block owns NC=8 columns (c0..c0+7):
//   prologue: stage X column-slab (4096 x 8 fp16, interleaved [m][c]) in LDS;
//             invert the 8 A-matrices (threads 0..127) into LDS.
//   2 iterations of: pass A (psi^2 -> sig, wave+block reduce),
//                    pass C (t accumulation, 2 column-halves),
//                    update (beta += mu * Ainv t) -- all sums in-block.
//   epilogue: write B (fp32+fp16), optional Pt build from final beta.
__global__ void __launch_bounds__(256, 2)
k_hub(const __half* __restrict__ Xsrc, const __half* __restrict__ Dh,
      const float* __restrict__ Apad, const float* __restrict__ sigma,
      const float* __restrict__ cnt, const float* __restrict__ cvec,
      const float* __restrict__ lvec, const float* __restrict__ mvec,
      int layer, float* __restrict__ B, __half* __restrict__ Bh,
      unsigned short* __restrict__ Pt, int do_pt) {
    __shared__ unsigned short Xs[DIM][NC];   // 64 KB: Xs[m][c] = X-elem (row m, col c0+c)
    __shared__ float ainv_s[NC][16][16];     // 8 KB
    __shared__ float red_s[4][NC][16];       // 2 KB (wave partials)
    __shared__ float t_sh[NC][16];
    __shared__ float beta_s[NC][16];
    __shared__ float sig_s[NC];
    const int tid = threadIdx.x;
    const int wv = tid >> 6, ln = tid & 63;
    const int c0 = blockIdx.x * NC;

    // ---- stage X slab: 16 B per row per block ----
#pragma unroll
    for (int k = 0; k < 16; ++k) {
        int m = tid + (k << 8);
        *(uint4*)&Xs[m][0] = *(const uint4*)(Xsrc + (size_t)m * DIM + c0);
    }
    if (tid < NC * 16)
        beta_s[tid >> 4][tid & 15] = B[(size_t)(c0 + (tid >> 4)) * RDIM + (tid & 15)];

    // ---- invert 8 SPD 16x16 (threads 0..127; 16-lane groups) ----
    if (tid < 128) {
        int cc = tid >> 4;
        int c = c0 + cc;
        int j = tid & 15;
        float a[16], b[16];
#pragma unroll
        for (int s = 0; s < 16; ++s) {
            int r0 = j < s ? j : s;
            int s0_ = j < s ? s : j;
            int off = pidx(r0, s0_);
            float ac = 0.f;
#pragma unroll
            for (int ch = 0; ch < KCH; ++ch)
                ac += Apad[((size_t)ch * DIM + c) * NPKP + off];
            a[s] = ac;
            b[s] = 0.f;
        }
        a[j] += RIDGE;
        b[j] = 1.f;
#pragma unroll
        for (int k = 0; k < RDIM; ++k) {
            float pivA[16], pivB[16];
#pragma unroll
            for (int s = 0; s < 16; ++s) {
                pivA[s] = __shfl(a[s], k, 16);
                pivB[s] = __shfl(b[s], k, 16);
            }
            float pinv = 1.f / pivA[k];
            float f = a[k];
            if (j == k) {
#pragma unroll
                for (int s = 0; s < 16; ++s) { a[s] = pivA[s] * pinv; b[s] = pivB[s] * pinv; }
            } else {
#pragma unroll
                for (int s = 0; s < 16; ++s) {
                    a[s] -= f * pinv * pivA[s];
                    b[s] -= f * pinv * pivB[s];
                }
            }
        }
#pragma unroll
        for (int s = 0; s < 16; ++s) ainv_s[cc][j][s] = b[s];
    }
    __syncthreads();

    const float cl = cvec[layer], ll = lvec[layer], ml = mvec[layer];
    const float al = alpha_of(cl);
    const float s0inv = 1.f / sigma[0];

    for (int it = 0; it < 2; ++it) {
        // ================= pass A: psi^2 =================
        float invs[NC];
#pragma unroll
        for (int c = 0; c < NC; ++c)
            invs[c] = (it == 0) ? s0inv : 1.f / sig_s[c];
        float bb[NC][16];
#pragma unroll
        for (int c = 0; c < NC; ++c)
#pragma unroll
            for (int q = 0; q < 4; ++q) {
                float4 b4 = *(float4*)&beta_s[c][q * 4];
                bb[c][q * 4 + 0] = b4.x; bb[c][q * 4 + 1] = b4.y;
                bb[c][q * 4 + 2] = b4.z; bb[c][q * 4 + 3] = b4.w;
            }
        float acc[NC];
#pragma unroll
        for (int c = 0; c < NC; ++c) acc[c] = 0.f;
        for (int k = 0; k < 16; ++k) {
            int m = tid + (k << 8);
            union { uint4 w; __half h[8]; } xu;
            xu.w = *(const uint4*)&Xs[m][0];
            union { uint4 w[2]; __half h[16]; } uu;
            uu.w[0] = *(const uint4*)(Dh + (size_t)m * RDIM);
            uu.w[1] = *(const uint4*)(Dh + (size_t)m * RDIM + 8);
            float u[16];
#pragma unroll
            for (int s = 0; s < 16; ++s) u[s] = __half2float(uu.h[s]);
#pragma unroll
            for (int c = 0; c < NC; ++c) {
                float xv = __half2float(xu.h[c]);
                float dot = 0.f;
#pragma unroll
                for (int s = 0; s < 16; ++s) dot += u[s] * bb[c][s];
                float res = (xv != 0.f) ? (xv - dot) : 0.f;
                float psi = fminf(fmaxf(res * invs[c], -cl), cl);
                acc[c] += psi * psi;
            }
        }
#pragma unroll
        for (int c = 0; c < NC; ++c) {
#pragma unroll
            for (int off = 1; off < 64; off <<= 1)
                acc[c] += __shfl_xor(acc[c], off, 64);
        }
        if (ln == 0) {
#pragma unroll
            for (int c = 0; c < NC; ++c) red_s[wv][c][0] = acc[c];
        }
        __syncthreads();
        if (tid < NC) {
            float sn = red_s[0][tid][0] + red_s[1][tid][0] +
                       red_s[2][tid][0] + red_s[3][tid][0];
            sig_s[tid] = ll * sqrtf(sn) * rsqrtf(2.f * cnt[c0 + tid] * al);
        }
        __syncthreads();

        // ================= pass C: t accumulation (two column-halves) ======
#pragma unroll
        for (int hf = 0; hf < 2; ++hf) {
            float sg[4], isg[4], bs[4][16], tac[4][16];
#pragma unroll
            for (int i = 0; i < 4; ++i) {
                sg[i] = sig_s[hf * 4 + i];
                isg[i] = 1.f / sg[i];
#pragma unroll
                for (int q = 0; q < 4; ++q) {
                    float4 b4 = *(float4*)&beta_s[hf * 4 + i][q * 4];
                    bs[i][q * 4 + 0] = b4.x; bs[i][q * 4 + 1] = b4.y;
                    bs[i][q * 4 + 2] = b4.z; bs[i][q * 4 + 3] = b4.w;
                }
#pragma unroll
                for (int s = 0; s < 16; ++s) tac[i][s] = 0.f;
            }
            for (int k = 0; k < 16; ++k) {
                int m = tid + (k << 8);
                union { uint2 w; __half h[4]; } xu;
                xu.w = *(const uint2*)&Xs[m][hf * 4];
                union { uint4 w[2]; __half h[16]; } uu;
                uu.w[0] = *(const uint4*)(Dh + (size_t)m * RDIM);
                uu.w[1] = *(const uint4*)(Dh + (size_t)m * RDIM + 8);
                float u[16];
#pragma unroll
                for (int s = 0; s < 16; ++s) u[s] = __half2float(uu.h[s]);
#pragma unroll
                for (int i = 0; i < 4; ++i) {
                    float xv = __half2float(xu.h[i]);
                    float dot = 0.f;
#pragma unroll
                    for (int s = 0; s < 16; ++s) dot += u[s] * bs[i][s];
                    float res = (xv != 0.f) ? (xv - dot) : 0.f;
                    float psi2 = fminf(fmaxf(res * isg[i], -cl), cl);
                    float coeff = psi2 * sg[i];
#pragma unroll
                    for (int s = 0; s < 16; ++s) tac[i][s] += u[s] * coeff;
                }
            }
#pragma unroll
            for (int i = 0; i < 4; ++i)
#pragma unroll
                for (int s = 0; s < 16; ++s) {
#pragma unroll
                    for (int off = 1; off < 64; off <<= 1)
                        tac[i][s] += __shfl_xor(tac[i][s], off, 64);
                }
            if (ln == 0) {
#pragma unroll
                for (int i = 0; i < 4; ++i)
#pragma unroll
                    for (int s = 0; s < 16; ++s)
                        red_s[wv][hf * 4 + i][s] = tac[i][s];
            }
        }
        __syncthreads();

        // ================= update: beta += mu * Ainv t =====================
        if (tid < 128) {
            int c = tid >> 4, j = tid & 15;
            t_sh[c][j] = red_s[0][c][j] + red_s[1][c][j] +
                         red_s[2][c][j] + red_s[3][c][j];
        }
        __syncthreads();
        if (tid < 128) {
            int c = tid >> 4, j = tid & 15;
            float d = 0.f;
#pragma unroll
            for (int q = 0; q < 4; ++q) {
                float4 a4 = *(float4*)&ainv_s[c][j][q * 4];
                d += a4.x * t_sh[c][q * 4 + 0] + a4.y * t_sh[c][q * 4 + 1] +
                     a4.z * t_sh[c][q * 4 + 2] + a4.w * t_sh[c][q * 4 + 3];
            }
            beta_s[c][j] += ml * d;
        }
        __syncthreads();
    }

    // ================= epilogue ===========================================
    if (tid < 128) {
        int c = tid >> 4, j = tid & 15;
        float bv = beta_s[c][j];
        B[(size_t)(c0 + c) * RDIM + j] = bv;
        Bh[(size_t)(c0 + c) * RDIM + j] = __float2half(bv);
    }
    if (do_pt && tid < 144) {
        int rs = tid;
        int rr = 16, ss = 0;
#pragma unroll
        for (int r = 0; r < 16; ++r) {
            int base = r * (31 - r) / 2;
            if (rs >= base + r && rs <= base + 15) { rr = r; ss = rs - base; }
        }
#pragma unroll
        for (int c = 0; c < NC; ++c) {
            float p = (rr < 16) ? beta_s[c][rr] * beta_s[c][ss] : 0.f;
            Pt[(size_t)rs * DIM + c0 + c] = bf16_rne(p);
        }
    }
}

// ---------------- final out = Uc @ Vtb^T -----------------------------------
__global__ void __launch_bounds__(256) k_out(const float* __restrict__ Uc,
                                             const float* __restrict__ Vtb,
                                             float* __restrict__ out) {
    __shared__ float us[64 * RDIM];
    int j = blockIdx.x * 256 + threadIdx.x;
    int i0 = blockIdx.y * 64;
    ((float4*)us)[threadIdx.x] = ((const float4*)(Uc + (size_t)i0 * RDIM))[threadIdx.x];
    float beta[16];
#pragma unroll
    for (int q = 0; q < 4; ++q) {
        float4 t4 = ((const float4*)(Vtb + (size_t)j * RDIM))[q];
        beta[q * 4 + 0] = t4.x; beta[q * 4 + 1] = t4.y;
        beta[q * 4 + 2] = t4.z; beta[q * 4 + 3] = t4.w;
    }
    __syncthreads();
#pragma unroll 4
    for (int r = 0; r < 64; ++r) {
        float dot = 0.f;
#pragma unroll
        for (int q = 0; q < 4; ++q) {
            float4 u4 = *(const float4*)(us + r * RDIM + q * 4);
            dot += u4.x * beta[q * 4 + 0] + u4.y * beta[q * 4 + 1] +
                   u4.z * beta[q * 4 + 2] + u4.w * beta[q * 4 + 3];
        }
        out[(size_t)(i0 + r) * DIM + j] = dot;
    }
}

extern "C" void kernel_launch(void* const* d_in, const int* in_sizes, int n_in,
                              void* d_out, int out_size, void* d_ws, size_t ws_size,
                              hipStream_t stream) {
    const float* U = (const float*)d_in[0];
    const float* V = (const float*)d_in[1];
    const float* X = (const float*)d_in[2];
    const float* cvec = (const float*)d_in[3];
    const float* lvec = (const float*)d_in[4];
    const float* mvec = (const float*)d_in[5];
    const float* sigma = (const float*)d_in[6];
    float* out = (float*)d_out;

    float* ws = (float*)d_ws;
    float* Apad = ws;                                   // KCH*DIM*NPKP = 4.72M f
    float* cntc = Apad + (size_t)KCH * DIM * NPKP;      // DIM
    float* cntr = cntc + DIM;                           // DIM
    float* Uc   = cntr + DIM;                           // DIM*16
    float* Vtb  = Uc + (size_t)DIM * RDIM;              // DIM*16
    __half* Uch  = (__half*)(Vtb + (size_t)DIM * RDIM); // DIM*16 halves
    __half* Vtbh = Uch + (size_t)DIM * RDIM;            // DIM*16 halves
    unsigned short* Pt = (unsigned short*)(Vtbh + (size_t)DIM * RDIM); // 144*DIM u16
    // fp16 X copies live in d_out (scratch until k_out): exactly fills out_size.
    __half* Xh  = (__half*)out;
    __half* XhT = Xh + (size_t)DIM * DIM;

    hipMemsetAsync(cntc, 0, (size_t)2 * DIM * sizeof(float), stream);

    k_transpose<<<dim3(64, 64), 256, 0, stream>>>(X, Xh, XhT, cntc, cntr);
    k_init_uc<<<64, 256, 0, stream>>>(U, Uc, Uch);
    k_init_vt<<<16, 256, 0, stream>>>(V, Vtb);
    k_prep<<<dim3(16, NPKP), 256, 0, stream>>>(Uc, Pt);

    for (int layer = 0; layer < 3; ++layer) {
        int last = (layer == 2);
        // ---- V step: design Uc/Uch; columns of X; mask rows from XhT ----
        k_buildA<<<512, 256, 0, stream>>>(XhT, Pt, Apad);
        k_hub<<<512, 256, 0, stream>>>(Xh, Uch, Apad, sigma, cntc,
                                       cvec, lvec, mvec, layer,
                                       Vtb, Vtbh, Pt, 1);
        // ---- U step: design Vtb/Vtbh; rows of X; mask rows from Xh ----
        k_buildA<<<512, 256, 0, stream>>>(Xh, Pt, Apad);
        k_hub<<<512, 256, 0, stream>>>(XhT, Vtbh, Apad, sigma, cntr,
                                       cvec, lvec, mvec, layer,
                                       Uc, Uch, last ? nullptr : Pt, last ? 0 : 1);
    }
    k_out<<<dim3(16, 64), 256, 0, stream>>>(Uc, Vtb, out);
}

// Round 7
// 884.986 us; speedup vs baseline: 1.3755x; 1.2968x over previous
//
#include <hip/hip_runtime.h>
#include <hip/hip_fp16.h>
#include <math.h>

#define DIM 4096
#define RDIM 16
#define RIDGE 1e-5f
#define NPKP 144    // padded pair count (9 MFMA tiles of 16)
#define KCH 8       // K-chunks for MFMA buildA
#define KT 128      // k-tile staged in LDS per buildA inner iteration
#define NC 4        // columns owned per k_hub block

typedef __attribute__((ext_vector_type(8))) short bf16x8;
typedef __attribute__((ext_vector_type(4))) float f32x4;

__device__ __forceinline__ int pidx(int r, int s) { return r * (31 - r) / 2 + s; } // r<=s

__device__ __forceinline__ float alpha_of(float cl) {
    return cl * (1.f - erff(sqrtf(cl))) +
           0.5f * (erff(cl * 0.70710678118f) -
                   0.79788456080f * cl * expf(-0.5f * cl * cl));
}

__device__ __forceinline__ unsigned short bf16_rne(float p) {
    unsigned bits = __float_as_uint(p);
    return (unsigned short)((bits + 0x7FFFu + ((bits >> 16) & 1u)) >> 16);
}

// half-pair u32 -> bf16 0/1 mask pair u32 (nonzero-magnitude test per half)
__device__ __forceinline__ unsigned mask2_of(unsigned w) {
    return ((w & 0x00007FFFu) ? 0x00003F80u : 0u) |
           ((w & 0x7FFF0000u) ? 0x3F800000u : 0u);
}

// ------- transpose: X(fp32) -> Xh (fp16, row-major) + XhT (fp16, transposed)
// fused per-column and per-row observed counts.
__global__ void __launch_bounds__(256) k_transpose(const float* __restrict__ X,
                                                   __half* __restrict__ Xh,
                                                   __half* __restrict__ XhT,
                                                   float* __restrict__ cntc,
                                                   float* __restrict__ cntr) {
    __shared__ float tile[64][65];
    __shared__ float redc[4][64];
    __shared__ float redr[4][64];
    int bx = blockIdx.x, by = blockIdx.y;
    int lx = threadIdx.x & 63;
    int ly = threadIdx.x >> 6;
    float ccnt = 0.f;
#pragma unroll
    for (int i = 0; i < 16; ++i) {
        int r = ly + i * 4;
        float v = X[(size_t)(by * 64 + r) * DIM + bx * 64 + lx];
        tile[r][lx] = v;
        Xh[(size_t)(by * 64 + r) * DIM + bx * 64 + lx] = __float2half(v);
        ccnt += (v != 0.f) ? 1.f : 0.f;
    }
    redc[ly][lx] = ccnt;
    __syncthreads();
#pragma unroll
    for (int i = 0; i < 16; ++i) {
        int r = ly + i * 4;
        XhT[(size_t)(bx * 64 + r) * DIM + by * 64 + lx] = __float2half(tile[lx][r]);
    }
    float rcnt = 0.f;
#pragma unroll
    for (int j = 0; j < 16; ++j)
        rcnt += (tile[lx][ly * 16 + j] != 0.f) ? 1.f : 0.f;
    redr[ly][lx] = rcnt;
    __syncthreads();
    if (threadIdx.x < 64) {
        int c = threadIdx.x;
        atomicAdd(&cntc[bx * 64 + c],
                  redc[0][c] + redc[1][c] + redc[2][c] + redc[3][c]);
    } else if (threadIdx.x < 128) {
        int r = threadIdx.x - 64;
        atomicAdd(&cntr[by * 64 + r],
                  redr[0][r] + redr[1][r] + redr[2][r] + redr[3][r]);
    }
}

// ---------------- init copies ----------------------------------------------
__global__ void k_init_uc(const float* __restrict__ U, float* __restrict__ Uc,
                          __half* __restrict__ Uch) {
    int i = blockIdx.x * 256 + threadIdx.x;
    float4 v = ((const float4*)U)[i];
    ((float4*)Uc)[i] = v;
    __half2 h0 = __floats2half2_rn(v.x, v.y);
    __half2 h1 = __floats2half2_rn(v.z, v.w);
    *(__half2*)(Uch + (size_t)i * 4)     = h0;
    *(__half2*)(Uch + (size_t)i * 4 + 2) = h1;
}
__global__ void k_init_vt(const float* __restrict__ V, float* __restrict__ Vtb) {
    int n = blockIdx.x * 256 + threadIdx.x;
#pragma unroll
    for (int r = 0; r < RDIM; ++r) Vtb[(size_t)n * RDIM + r] = V[(size_t)r * DIM + n];
}

// ---------------- Pt[rs][m] = bf16(D[m][r] * D[m][s]), pidx order ----------
// Only used ONCE (layer-0 V step); later Pt builds fused into k_hub epilogue.
__global__ void __launch_bounds__(256) k_prep(const float* __restrict__ D,
                                              unsigned short* __restrict__ Pt) {
    int rs = blockIdx.y;
    int rr = 16, ss = 0;
#pragma unroll
    for (int r = 0; r < 16; ++r) {
        int base = r * (31 - r) / 2;
        if (rs >= base + r && rs <= base + 15) { rr = r; ss = rs - base; }
    }
    int m = blockIdx.x * 256 + threadIdx.x;
    float p = 0.f;
    if (rr < 16) p = D[(size_t)m * RDIM + rr] * D[(size_t)m * RDIM + ss];
    Pt[(size_t)rs * DIM + m] = bf16_rne(p);
}

// ---------------- MFMA buildA, KT=128, 16B staging loads -------------------
// grid 512: (bid&63) = c-block of 64, (bid>>6) = k-chunk (0..7, 512 k each).
__global__ void __launch_bounds__(256) k_buildA(const __half* __restrict__ XphT,
                                                const unsigned short* __restrict__ Pt,
                                                float* __restrict__ Apad) {
    __shared__ unsigned short wtile[64][KT + 8];
    __shared__ unsigned short ptile[144][KT + 8];
    const int tid = threadIdx.x;
    const int wave = tid >> 6;
    const int lane = tid & 63;
    const int n = lane & 15;
    const int quad = lane >> 4;
    const int c0 = (blockIdx.x & 63) * 64;
    const int kch = blockIdx.x >> 6;
    const int kbase0 = kch * (DIM / KCH);

    f32x4 acc[9];
#pragma unroll
    for (int t = 0; t < 9; ++t) acc[t] = (f32x4){0.f, 0.f, 0.f, 0.f};

    for (int kt = 0; kt < (DIM / KCH) / KT; ++kt) {   // 4 iterations
        const int kb = kbase0 + kt * KT;
        __syncthreads();
#pragma unroll
        for (int j = 0; j < 4; ++j) {
            int idx = j * 256 + tid;
            int r = idx >> 4;
            int ccol = (idx & 15) * 8;
            uint4 v = *(const uint4*)(XphT + (size_t)(c0 + r) * DIM + kb + ccol);
            uint4 mk;
            mk.x = mask2_of(v.x);
            mk.y = mask2_of(v.y);
            mk.z = mask2_of(v.z);
            mk.w = mask2_of(v.w);
            *(uint4*)&wtile[r][ccol] = mk;
        }
#pragma unroll
        for (int j = 0; j < 9; ++j) {
            int idx = j * 256 + tid;
            int pr = idx >> 4;
            int pc = (idx & 15) * 8;
            *(uint4*)&ptile[pr][pc] = *(const uint4*)(Pt + (size_t)pr * DIM + kb + pc);
        }
        __syncthreads();
#pragma unroll
        for (int inner = 0; inner < 4; ++inner) {
            bf16x8 bfrag = *(const bf16x8*)&wtile[wave * 16 + n][inner * 32 + quad * 8];
#pragma unroll
            for (int t = 0; t < 9; ++t) {
                bf16x8 afrag = *(const bf16x8*)&ptile[t * 16 + n][inner * 32 + quad * 8];
                acc[t] = __builtin_amdgcn_mfma_f32_16x16x32_bf16(afrag, bfrag, acc[t], 0, 0, 0);
            }
        }
    }
    const int c = c0 + wave * 16 + n;
    float* dst0 = Apad + ((size_t)kch * DIM + c) * NPKP + quad * 4;
#pragma unroll
    for (int t = 0; t < 9; ++t)
        *(float4*)(dst0 + t * 16) = (float4){acc[t].x, acc[t].y, acc[t].z, acc[t].w};
}

// =================== fused per-column hubreg solver ========================
// grid 1024 blocks x 256 thr. Block owns NC=4 columns (c0..c0+3).
//   prologue: coalesced-stage the 4 matching rows of the T-oriented fp16 X
//             (columns of X are contiguous rows of XsrcT); invert the 4
//             A-matrices (threads 0..63) into LDS.
//   2 iterations of: pass A (psi^2 -> sig, tree reduce),
//                    pass C (t accumulation, 2 x 2-column sub-passes),
//                    update (beta += mu * Ainv t) -- all in-block.
//   epilogue: write B (fp32+fp16), optional Pt build from final beta.
__global__ void __launch_bounds__(256, 4)
k_hub(const __half* __restrict__ XsrcT, const __half* __restrict__ Dh,
      const float* __restrict__ Apad, const float* __restrict__ sigma,
      const float* __restrict__ cnt, const float* __restrict__ cvec,
      const float* __restrict__ lvec, const float* __restrict__ mvec,
      int layer, float* __restrict__ B, __half* __restrict__ Bh,
      unsigned short* __restrict__ Pt, int do_pt) {
    __shared__ __align__(16) __half Xcol[NC * DIM];   // 32 KB, [c][m] linear
    __shared__ float ainv_s[NC][16][16];              // 4 KB
    __shared__ float red_s[4][64];                    // 1 KB
    __shared__ float t_sh[NC][16];
    __shared__ float beta_s[NC][16];
    __shared__ float sig_s[NC];
    const int tid = threadIdx.x;
    const int wv = tid >> 6, ln = tid & 63;
    const int c0 = blockIdx.x * NC;

    // ---- stage: NC contiguous rows of XsrcT, fully coalesced uint4 copy ----
    {
        const uint4* src = (const uint4*)(XsrcT + (size_t)c0 * DIM);
        uint4* dst = (uint4*)Xcol;
#pragma unroll
        for (int q = 0; q < (NC * DIM) / (256 * 8); ++q)   // 8 iterations
            dst[q * 256 + tid] = src[q * 256 + tid];
    }
    if (tid >= 128 && tid < 128 + NC * 16) {
        int t2 = tid - 128;
        beta_s[t2 >> 4][t2 & 15] = B[(size_t)(c0 + (t2 >> 4)) * RDIM + (t2 & 15)];
    }
    // ---- invert NC SPD 16x16 (threads 0..63; 16-lane groups) ----
    if (tid < NC * 16) {
        int cc = tid >> 4;
        int c = c0 + cc;
        int j = tid & 15;
        float a[16], b[16];
#pragma unroll
        for (int s = 0; s < 16; ++s) {
            int r0 = j < s ? j : s;
            int s0_ = j < s ? s : j;
            int off = pidx(r0, s0_);
            float ac = 0.f;
#pragma unroll
            for (int ch = 0; ch < KCH; ++ch)
                ac += Apad[((size_t)ch * DIM + c) * NPKP + off];
            a[s] = ac;
            b[s] = 0.f;
        }
        a[j] += RIDGE;
        b[j] = 1.f;
#pragma unroll
        for (int k = 0; k < RDIM; ++k) {
            float pivA[16], pivB[16];
#pragma unroll
            for (int s = 0; s < 16; ++s) {
                pivA[s] = __shfl(a[s], k, 16);
                pivB[s] = __shfl(b[s], k, 16);
            }
            float pinv = 1.f / pivA[k];
            float f = a[k];
            if (j == k) {
#pragma unroll
                for (int s = 0; s < 16; ++s) { a[s] = pivA[s] * pinv; b[s] = pivB[s] * pinv; }
            } else {
#pragma unroll
                for (int s = 0; s < 16; ++s) {
                    a[s] -= f * pinv * pivA[s];
                    b[s] -= f * pinv * pivB[s];
                }
            }
        }
#pragma unroll
        for (int s = 0; s < 16; ++s) ainv_s[cc][j][s] = b[s];
    }
    __syncthreads();

    const float cl = cvec[layer], ll = lvec[layer], ml = mvec[layer];
    const float al = alpha_of(cl);
    const float s0inv = 1.f / sigma[0];

    for (int it = 0; it < 2; ++it) {
        // ================= pass A: psi^2 -> sig ===========================
        {
            float invs[NC];
#pragma unroll
            for (int c = 0; c < NC; ++c)
                invs[c] = (it == 0) ? s0inv : 1.f / sig_s[c];
            float bb[NC][16];
#pragma unroll
            for (int c = 0; c < NC; ++c)
#pragma unroll
                for (int q = 0; q < 4; ++q) {
                    float4 b4 = *(float4*)&beta_s[c][q * 4];
                    bb[c][q * 4 + 0] = b4.x; bb[c][q * 4 + 1] = b4.y;
                    bb[c][q * 4 + 2] = b4.z; bb[c][q * 4 + 3] = b4.w;
                }
            float acc[NC];
#pragma unroll
            for (int c = 0; c < NC; ++c) acc[c] = 0.f;
#pragma unroll 2
            for (int k = 0; k < 16; ++k) {
                int m = tid + (k << 8);
                union { uint4 w[2]; __half h[16]; } uu;
                uu.w[0] = *(const uint4*)(Dh + (size_t)m * RDIM);
                uu.w[1] = *(const uint4*)(Dh + (size_t)m * RDIM + 8);
                float u[16];
#pragma unroll
                for (int s = 0; s < 16; ++s) u[s] = __half2float(uu.h[s]);
#pragma unroll
                for (int c = 0; c < NC; ++c) {
                    float xv = __half2float(Xcol[c * DIM + m]);
                    float dot = 0.f;
#pragma unroll
                    for (int s = 0; s < 16; ++s) dot += u[s] * bb[c][s];
                    float res = (xv != 0.f) ? (xv - dot) : 0.f;
                    float psi = fminf(fmaxf(res * invs[c], -cl), cl);
                    acc[c] += psi * psi;
                }
            }
            // wave tree-reduce: 4 values -> lane (ln&3) holds wave total of col ln&3
            int h1 = (ln >> 1) & 1;
            float k0 = h1 ? acc[2] : acc[0], s0_ = h1 ? acc[0] : acc[2];
            float k1 = h1 ? acc[3] : acc[1], s1_ = h1 ? acc[1] : acc[3];
            float r0 = k0 + __shfl_xor(s0_, 2, 64);
            float r1 = k1 + __shfl_xor(s1_, 2, 64);
            int h0 = ln & 1;
            float kk = h0 ? r1 : r0, ss_ = h0 ? r0 : r1;
            float v = kk + __shfl_xor(ss_, 1, 64);
#pragma unroll
            for (int off = 4; off < 64; off <<= 1)
                v += __shfl_xor(v, off, 64);
            if (ln < NC) red_s[wv][ln] = v;
        }
        __syncthreads();
        if (tid < NC) {
            float sn = red_s[0][tid] + red_s[1][tid] + red_s[2][tid] + red_s[3][tid];
            sig_s[tid] = ll * sqrtf(sn) * rsqrtf(2.f * cnt[c0 + tid] * al);
        }
        __syncthreads();

        // ================= pass C: t accumulation (2 x 2-column) ==========
#pragma unroll
        for (int hf = 0; hf < 2; ++hf) {
            float sg[2], isg[2], bs[2][16];
            float v[32];   // tac flattened: idx = i*16+s
#pragma unroll
            for (int i = 0; i < 2; ++i) {
                sg[i] = sig_s[hf * 2 + i];
                isg[i] = 1.f / sg[i];
#pragma unroll
                for (int q = 0; q < 4; ++q) {
                    float4 b4 = *(float4*)&beta_s[hf * 2 + i][q * 4];
                    bs[i][q * 4 + 0] = b4.x; bs[i][q * 4 + 1] = b4.y;
                    bs[i][q * 4 + 2] = b4.z; bs[i][q * 4 + 3] = b4.w;
                }
            }
#pragma unroll
            for (int j = 0; j < 32; ++j) v[j] = 0.f;
#pragma unroll 2
            for (int k = 0; k < 16; ++k) {
                int m = tid + (k << 8);
                union { uint4 w[2]; __half h[16]; } uu;
                uu.w[0] = *(const uint4*)(Dh + (size_t)m * RDIM);
                uu.w[1] = *(const uint4*)(Dh + (size_t)m * RDIM + 8);
                float u[16];
#pragma unroll
                for (int s = 0; s < 16; ++s) u[s] = __half2float(uu.h[s]);
#pragma unroll
                for (int i = 0; i < 2; ++i) {
                    float xv = __half2float(Xcol[(hf * 2 + i) * DIM + m]);
                    float dot = 0.f;
#pragma unroll
                    for (int s = 0; s < 16; ++s) dot += u[s] * bs[i][s];
                    float res = (xv != 0.f) ? (xv - dot) : 0.f;
                    float psi2 = fminf(fmaxf(res * isg[i], -cl), cl);
                    float coeff = psi2 * sg[i];
#pragma unroll
                    for (int s = 0; s < 16; ++s) v[i * 16 + s] += u[s] * coeff;
                }
            }
            // wave tree-reduce 32 values -> lane (ln&31); value selects, no
            // runtime array indexing (rule #20).
#pragma unroll
            for (int b = 4; b >= 0; --b) {
                const int half = 1 << b;
                int hi = (ln >> b) & 1;
#pragma unroll
                for (int j = 0; j < half; ++j) {
                    float lo_v = v[j], hi_v = v[j + half];
                    float keep = hi ? hi_v : lo_v;
                    float send = hi ? lo_v : hi_v;
                    v[j] = keep + __shfl_xor(send, half, 64);
                }
            }
            float tv = v[0] + __shfl_xor(v[0], 32, 64);
            if (ln < 32) red_s[wv][hf * 32 + ln] = tv;
        }
        __syncthreads();

        // ================= update: beta += mu * Ainv t =====================
        if (tid < 64)
            t_sh[tid >> 4][tid & 15] = red_s[0][tid] + red_s[1][tid] +
                                       red_s[2][tid] + red_s[3][tid];
        __syncthreads();
        if (tid < 64) {
            int c = tid >> 4, j = tid & 15;
            float d = 0.f;
#pragma unroll
            for (int q = 0; q < 4; ++q) {
                float4 a4 = *(float4*)&ainv_s[c][j][q * 4];
                d += a4.x * t_sh[c][q * 4 + 0] + a4.y * t_sh[c][q * 4 + 1] +
                     a4.z * t_sh[c][q * 4 + 2] + a4.w * t_sh[c][q * 4 + 3];
            }
            beta_s[c][j] += ml * d;
        }
        __syncthreads();
    }

    // ================= epilogue ===========================================
    if (tid < NC * 16) {
        int c = tid >> 4, j = tid & 15;
        float bv = beta_s[c][j];
        B[(size_t)(c0 + c) * RDIM + j] = bv;
        Bh[(size_t)(c0 + c) * RDIM + j] = __float2half(bv);
    }
    if (do_pt && tid >= 112 && tid < 256) {
        int rs = tid - 112;
        int rr = 16, ss = 0;
#pragma unroll
        for (int r = 0; r < 16; ++r) {
            int base = r * (31 - r) / 2;
            if (rs >= base + r && rs <= base + 15) { rr = r; ss = rs - base; }
        }
#pragma unroll
        for (int c = 0; c < NC; ++c) {
            float p = (rr < 16) ? beta_s[c][rr] * beta_s[c][ss] : 0.f;
            Pt[(size_t)rs * DIM + c0 + c] = bf16_rne(p);
        }
    }
}

// ---------------- final out = Uc @ Vtb^T -----------------------------------
__global__ void __launch_bounds__(256) k_out(const float* __restrict__ Uc,
                                             const float* __restrict__ Vtb,
                                             float* __restrict__ out) {
    __shared__ float us[64 * RDIM];
    int j = blockIdx.x * 256 + threadIdx.x;
    int i0 = blockIdx.y * 64;
    ((float4*)us)[threadIdx.x] = ((const float4*)(Uc + (size_t)i0 * RDIM))[threadIdx.x];
    float beta[16];
#pragma unroll
    for (int q = 0; q < 4; ++q) {
        float4 t4 = ((const float4*)(Vtb + (size_t)j * RDIM))[q];
        beta[q * 4 + 0] = t4.x; beta[q * 4 + 1] = t4.y;
        beta[q * 4 + 2] = t4.z; beta[q * 4 + 3] = t4.w;
    }
    __syncthreads();
#pragma unroll 4
    for (int r = 0; r < 64; ++r) {
        float dot = 0.f;
#pragma unroll
        for (int q = 0; q < 4; ++q) {
            float4 u4 = *(const float4*)(us + r * RDIM + q * 4);
            dot += u4.x * beta[q * 4 + 0] + u4.y * beta[q * 4 + 1] +
                   u4.z * beta[q * 4 + 2] + u4.w * beta[q * 4 + 3];
        }
        out[(size_t)(i0 + r) * DIM + j] = dot;
    }
}

extern "C" void kernel_launch(void* const* d_in, const int* in_sizes, int n_in,
                              void* d_out, int out_size, void* d_ws, size_t ws_size,
                              hipStream_t stream) {
    const float* U = (const float*)d_in[0];
    const float* V = (const float*)d_in[1];
    const float* X = (const float*)d_in[2];
    const float* cvec = (const float*)d_in[3];
    const float* lvec = (const float*)d_in[4];
    const float* mvec = (const float*)d_in[5];
    const float* sigma = (const float*)d_in[6];
    float* out = (float*)d_out;

    float* ws = (float*)d_ws;
    float* Apad = ws;                                   // KCH*DIM*NPKP = 4.72M f
    float* cntc = Apad + (size_t)KCH * DIM * NPKP;      // DIM
    float* cntr = cntc + DIM;                           // DIM
    float* Uc   = cntr + DIM;                           // DIM*16
    float* Vtb  = Uc + (size_t)DIM * RDIM;              // DIM*16
    __half* Uch  = (__half*)(Vtb + (size_t)DIM * RDIM); // DIM*16 halves
    __half* Vtbh = Uch + (size_t)DIM * RDIM;            // DIM*16 halves
    unsigned short* Pt = (unsigned short*)(Vtbh + (size_t)DIM * RDIM); // 144*DIM u16
    // fp16 X copies live in d_out (scratch until k_out): exactly fills out_size.
    __half* Xh  = (__half*)out;
    __half* XhT = Xh + (size_t)DIM * DIM;

    hipMemsetAsync(cntc, 0, (size_t)2 * DIM * sizeof(float), stream);

    k_transpose<<<dim3(64, 64), 256, 0, stream>>>(X, Xh, XhT, cntc, cntr);
    k_init_uc<<<64, 256, 0, stream>>>(U, Uc, Uch);
    k_init_vt<<<16, 256, 0, stream>>>(V, Vtb);
    k_prep<<<dim3(16, NPKP), 256, 0, stream>>>(Uc, Pt);

    for (int layer = 0; layer < 3; ++layer) {
        int last = (layer == 2);
        // ---- V step: design Uc/Uch; solved entities = columns of X, which
        //      are contiguous rows of XhT (both buildA and hub read XhT) ----
        k_buildA<<<512, 256, 0, stream>>>(XhT, Pt, Apad);
        k_hub<<<1024, 256, 0, stream>>>(XhT, Uch, Apad, sigma, cntc,
                                        cvec, lvec, mvec, layer,
                                        Vtb, Vtbh, Pt, 1);
        // ---- U step: design Vtb/Vtbh; solved entities = rows of X ----
        k_buildA<<<512, 256, 0, stream>>>(Xh, Pt, Apad);
        k_hub<<<1024, 256, 0, stream>>>(Xh, Vtbh, Apad, sigma, cntr,
                                        cvec, lvec, mvec, layer,
                                        Uc, Uch, last ? nullptr : Pt, last ? 0 : 1);
    }
    k_out<<<dim3(16, 64), 256, 0, stream>>>(Uc, Vtb, out);
}

// Round 8
// 744.292 us; speedup vs baseline: 1.6355x; 1.1890x over previous
//
#include <hip/hip_runtime.h>
#include <hip/hip_fp16.h>
#include <math.h>

#define DIM 4096
#define RDIM 16
#define RIDGE 1e-5f
#define NPKP 144    // padded pair count (9 MFMA tiles of 16)
#define KCH 8       // K-chunks for MFMA buildA
#define KT 128      // k-tile staged in LDS per buildA inner iteration
#define NC 4        // columns owned per k_hub block

typedef __attribute__((ext_vector_type(8))) short bf16x8;
typedef __attribute__((ext_vector_type(4))) float f32x4;
typedef _Float16 hf2 __attribute__((ext_vector_type(2)));

#if defined(__has_builtin)
#if __has_builtin(__builtin_amdgcn_fdot2)
#define HAVE_FDOT2 1
#endif
#endif

__device__ __forceinline__ int pidx(int r, int s) { return r * (31 - r) / 2 + s; } // r<=s

__device__ __forceinline__ float alpha_of(float cl) {
    return cl * (1.f - erff(sqrtf(cl))) +
           0.5f * (erff(cl * 0.70710678118f) -
                   0.79788456080f * cl * expf(-0.5f * cl * cl));
}

__device__ __forceinline__ unsigned short bf16_rne(float p) {
    unsigned bits = __float_as_uint(p);
    return (unsigned short)((bits + 0x7FFFu + ((bits >> 16) & 1u)) >> 16);
}

// half-pair u32 -> bf16 0/1 mask pair u32 (nonzero-magnitude test per half)
__device__ __forceinline__ unsigned mask2_of(unsigned w) {
    return ((w & 0x00007FFFu) ? 0x00003F80u : 0u) |
           ((w & 0x7FFF0000u) ? 0x3F800000u : 0u);
}

// 16-elem dot of a fp16 row (8 packed u32 words) with fp16 beta (8 x hf2),
// fp32 accumulate. v_dot2_f32_f16 when available.
__device__ __forceinline__ float dot16(const unsigned* uw, const hf2* b2) {
    float d = 0.f;
#if HAVE_FDOT2
#pragma unroll
    for (int q = 0; q < 8; ++q) {
        union { unsigned u; hf2 h; } cv;
        cv.u = uw[q];
        d = __builtin_amdgcn_fdot2(cv.h, b2[q], d, false);
    }
#else
#pragma unroll
    for (int q = 0; q < 8; ++q) {
        union { unsigned u; hf2 h; } cv;
        cv.u = uw[q];
        d += (float)cv.h[0] * (float)b2[q][0] + (float)cv.h[1] * (float)b2[q][1];
    }
#endif
    return d;
}

// ------- transpose: X(fp32) -> Xh (fp16, row-major) + XhT (fp16, transposed)
// fused per-column and per-row observed counts.
__global__ void __launch_bounds__(256) k_transpose(const float* __restrict__ X,
                                                   __half* __restrict__ Xh,
                                                   __half* __restrict__ XhT,
                                                   float* __restrict__ cntc,
                                                   float* __restrict__ cntr) {
    __shared__ float tile[64][65];
    __shared__ float redc[4][64];
    __shared__ float redr[4][64];
    int bx = blockIdx.x, by = blockIdx.y;
    int lx = threadIdx.x & 63;
    int ly = threadIdx.x >> 6;
    float ccnt = 0.f;
#pragma unroll
    for (int i = 0; i < 16; ++i) {
        int r = ly + i * 4;
        float v = X[(size_t)(by * 64 + r) * DIM + bx * 64 + lx];
        tile[r][lx] = v;
        Xh[(size_t)(by * 64 + r) * DIM + bx * 64 + lx] = __float2half(v);
        ccnt += (v != 0.f) ? 1.f : 0.f;
    }
    redc[ly][lx] = ccnt;
    __syncthreads();
#pragma unroll
    for (int i = 0; i < 16; ++i) {
        int r = ly + i * 4;
        XhT[(size_t)(bx * 64 + r) * DIM + by * 64 + lx] = __float2half(tile[lx][r]);
    }
    float rcnt = 0.f;
#pragma unroll
    for (int j = 0; j < 16; ++j)
        rcnt += (tile[lx][ly * 16 + j] != 0.f) ? 1.f : 0.f;
    redr[ly][lx] = rcnt;
    __syncthreads();
    if (threadIdx.x < 64) {
        int c = threadIdx.x;
        atomicAdd(&cntc[bx * 64 + c],
                  redc[0][c] + redc[1][c] + redc[2][c] + redc[3][c]);
    } else if (threadIdx.x < 128) {
        int r = threadIdx.x - 64;
        atomicAdd(&cntr[by * 64 + r],
                  redr[0][r] + redr[1][r] + redr[2][r] + redr[3][r]);
    }
}

// ---------------- init copies ----------------------------------------------
__global__ void k_init_uc(const float* __restrict__ U, float* __restrict__ Uc,
                          __half* __restrict__ Uch) {
    int i = blockIdx.x * 256 + threadIdx.x;
    float4 v = ((const float4*)U)[i];
    ((float4*)Uc)[i] = v;
    __half2 h0 = __floats2half2_rn(v.x, v.y);
    __half2 h1 = __floats2half2_rn(v.z, v.w);
    *(__half2*)(Uch + (size_t)i * 4)     = h0;
    *(__half2*)(Uch + (size_t)i * 4 + 2) = h1;
}
__global__ void k_init_vt(const float* __restrict__ V, float* __restrict__ Vtb) {
    int n = blockIdx.x * 256 + threadIdx.x;
#pragma unroll
    for (int r = 0; r < RDIM; ++r) Vtb[(size_t)n * RDIM + r] = V[(size_t)r * DIM + n];
}

// ---------------- Pt[rs][m] = bf16(D[m][r] * D[m][s]), pidx order ----------
// Only used ONCE (layer-0 V step); later Pt builds fused into k_hub epilogue.
__global__ void __launch_bounds__(256) k_prep(const float* __restrict__ D,
                                              unsigned short* __restrict__ Pt) {
    int rs = blockIdx.y;
    int rr = 16, ss = 0;
#pragma unroll
    for (int r = 0; r < 16; ++r) {
        int base = r * (31 - r) / 2;
        if (rs >= base + r && rs <= base + 15) { rr = r; ss = rs - base; }
    }
    int m = blockIdx.x * 256 + threadIdx.x;
    float p = 0.f;
    if (rr < 16) p = D[(size_t)m * RDIM + rr] * D[(size_t)m * RDIM + ss];
    Pt[(size_t)rs * DIM + m] = bf16_rne(p);
}

// ---------------- MFMA buildA, KT=128, 16B staging loads -------------------
// grid 512: (bid&63) = c-block of 64, (bid>>6) = k-chunk (0..7, 512 k each).
__global__ void __launch_bounds__(256) k_buildA(const __half* __restrict__ XphT,
                                                const unsigned short* __restrict__ Pt,
                                                float* __restrict__ Apad) {
    __shared__ unsigned short wtile[64][KT + 8];
    __shared__ unsigned short ptile[144][KT + 8];
    const int tid = threadIdx.x;
    const int wave = tid >> 6;
    const int lane = tid & 63;
    const int n = lane & 15;
    const int quad = lane >> 4;
    const int c0 = (blockIdx.x & 63) * 64;
    const int kch = blockIdx.x >> 6;
    const int kbase0 = kch * (DIM / KCH);

    f32x4 acc[9];
#pragma unroll
    for (int t = 0; t < 9; ++t) acc[t] = (f32x4){0.f, 0.f, 0.f, 0.f};

    for (int kt = 0; kt < (DIM / KCH) / KT; ++kt) {   // 4 iterations
        const int kb = kbase0 + kt * KT;
        __syncthreads();
#pragma unroll
        for (int j = 0; j < 4; ++j) {
            int idx = j * 256 + tid;
            int r = idx >> 4;
            int ccol = (idx & 15) * 8;
            uint4 v = *(const uint4*)(XphT + (size_t)(c0 + r) * DIM + kb + ccol);
            uint4 mk;
            mk.x = mask2_of(v.x);
            mk.y = mask2_of(v.y);
            mk.z = mask2_of(v.z);
            mk.w = mask2_of(v.w);
            *(uint4*)&wtile[r][ccol] = mk;
        }
#pragma unroll
        for (int j = 0; j < 9; ++j) {
            int idx = j * 256 + tid;
            int pr = idx >> 4;
            int pc = (idx & 15) * 8;
            *(uint4*)&ptile[pr][pc] = *(const uint4*)(Pt + (size_t)pr * DIM + kb + pc);
        }
        __syncthreads();
#pragma unroll
        for (int inner = 0; inner < 4; ++inner) {
            bf16x8 bfrag = *(const bf16x8*)&wtile[wave * 16 + n][inner * 32 + quad * 8];
#pragma unroll
            for (int t = 0; t < 9; ++t) {
                bf16x8 afrag = *(const bf16x8*)&ptile[t * 16 + n][inner * 32 + quad * 8];
                acc[t] = __builtin_amdgcn_mfma_f32_16x16x32_bf16(afrag, bfrag, acc[t], 0, 0, 0);
            }
        }
    }
    const int c = c0 + wave * 16 + n;
    float* dst0 = Apad + ((size_t)kch * DIM + c) * NPKP + quad * 4;
#pragma unroll
    for (int t = 0; t < 9; ++t)
        *(float4*)(dst0 + t * 16) = (float4){acc[t].x, acc[t].y, acc[t].z, acc[t].w};
}

// =================== fused per-column hubreg solver ========================
// grid 1024 blocks x 256 thr. Block owns NC=4 columns (c0..c0+3).
// Inner math uses v_dot2_f32_f16 (fp16 pair dot, fp32 accumulate) and
// mixed-precision fma (fp16 operand extended in the fma) to cut VALU ops.
__global__ void __launch_bounds__(256, 4)
k_hub(const __half* __restrict__ XsrcT, const __half* __restrict__ Dh,
      const float* __restrict__ Apad, const float* __restrict__ sigma,
      const float* __restrict__ cnt, const float* __restrict__ cvec,
      const float* __restrict__ lvec, const float* __restrict__ mvec,
      int layer, float* __restrict__ B, __half* __restrict__ Bh,
      unsigned short* __restrict__ Pt, int do_pt) {
    __shared__ __align__(16) __half Xcol[NC * DIM];   // 32 KB, [c][m] linear
    __shared__ float ainv_s[NC][16][16];              // 4 KB
    __shared__ float red_s[4][64];                    // 1 KB
    __shared__ float t_sh[NC][16];
    __shared__ float beta_s[NC][16];
    __shared__ float sig_s[NC];
    const int tid = threadIdx.x;
    const int wv = tid >> 6, ln = tid & 63;
    const int c0 = blockIdx.x * NC;

    // ---- stage: NC contiguous rows of XsrcT, fully coalesced uint4 copy ----
    {
        const uint4* src = (const uint4*)(XsrcT + (size_t)c0 * DIM);
        uint4* dst = (uint4*)Xcol;
#pragma unroll
        for (int q = 0; q < (NC * DIM) / (256 * 8); ++q)   // 8 iterations
            dst[q * 256 + tid] = src[q * 256 + tid];
    }
    if (tid >= 128 && tid < 128 + NC * 16) {
        int t2 = tid - 128;
        beta_s[t2 >> 4][t2 & 15] = B[(size_t)(c0 + (t2 >> 4)) * RDIM + (t2 & 15)];
    }
    // ---- invert NC SPD 16x16 (threads 0..63; 16-lane groups) ----
    if (tid < NC * 16) {
        int cc = tid >> 4;
        int c = c0 + cc;
        int j = tid & 15;
        float a[16], b[16];
#pragma unroll
        for (int s = 0; s < 16; ++s) {
            int r0 = j < s ? j : s;
            int s0_ = j < s ? s : j;
            int off = pidx(r0, s0_);
            float ac = 0.f;
#pragma unroll
            for (int ch = 0; ch < KCH; ++ch)
                ac += Apad[((size_t)ch * DIM + c) * NPKP + off];
            a[s] = ac;
            b[s] = 0.f;
        }
        a[j] += RIDGE;
        b[j] = 1.f;
#pragma unroll
        for (int k = 0; k < RDIM; ++k) {
            float pivA[16], pivB[16];
#pragma unroll
            for (int s = 0; s < 16; ++s) {
                pivA[s] = __shfl(a[s], k, 16);
                pivB[s] = __shfl(b[s], k, 16);
            }
            float pinv = 1.f / pivA[k];
            float f = a[k];
            if (j == k) {
#pragma unroll
                for (int s = 0; s < 16; ++s) { a[s] = pivA[s] * pinv; b[s] = pivB[s] * pinv; }
            } else {
#pragma unroll
                for (int s = 0; s < 16; ++s) {
                    a[s] -= f * pinv * pivA[s];
                    b[s] -= f * pinv * pivB[s];
                }
            }
        }
#pragma unroll
        for (int s = 0; s < 16; ++s) ainv_s[cc][j][s] = b[s];
    }
    __syncthreads();

    const float cl = cvec[layer], ll = lvec[layer], ml = mvec[layer];
    const float al = alpha_of(cl);
    const float s0inv = 1.f / sigma[0];

    for (int it = 0; it < 2; ++it) {
        // ================= pass A: psi^2 -> sig ===========================
        {
            float invs[NC];
#pragma unroll
            for (int c = 0; c < NC; ++c)
                invs[c] = (it == 0) ? s0inv : 1.f / sig_s[c];
            hf2 bb2[NC][8];
#pragma unroll
            for (int c = 0; c < NC; ++c)
#pragma unroll
                for (int q = 0; q < 8; ++q)
                    bb2[c][q] = hf2{(_Float16)beta_s[c][2 * q],
                                    (_Float16)beta_s[c][2 * q + 1]};
            float acc[NC];
#pragma unroll
            for (int c = 0; c < NC; ++c) acc[c] = 0.f;
#pragma unroll 2
            for (int k = 0; k < 16; ++k) {
                int m = tid + (k << 8);
                union { uint4 w[2]; unsigned u[8]; } uu;
                uu.w[0] = *(const uint4*)(Dh + (size_t)m * RDIM);
                uu.w[1] = *(const uint4*)(Dh + (size_t)m * RDIM + 8);
#pragma unroll
                for (int c = 0; c < NC; ++c) {
                    float xv = __half2float(Xcol[c * DIM + m]);
                    float dot = dot16(uu.u, bb2[c]);
                    float res = (xv != 0.f) ? (xv - dot) : 0.f;
                    float psi = fminf(fmaxf(res * invs[c], -cl), cl);
                    acc[c] = fmaf(psi, psi, acc[c]);
                }
            }
            // wave tree-reduce: 4 values -> lane (ln&3) holds wave total
            int h1 = (ln >> 1) & 1;
            float k0 = h1 ? acc[2] : acc[0], s0_ = h1 ? acc[0] : acc[2];
            float k1 = h1 ? acc[3] : acc[1], s1_ = h1 ? acc[1] : acc[3];
            float r0 = k0 + __shfl_xor(s0_, 2, 64);
            float r1 = k1 + __shfl_xor(s1_, 2, 64);
            int h0 = ln & 1;
            float kk = h0 ? r1 : r0, ss_ = h0 ? r0 : r1;
            float v = kk + __shfl_xor(ss_, 1, 64);
#pragma unroll
            for (int off = 4; off < 64; off <<= 1)
                v += __shfl_xor(v, off, 64);
            if (ln < NC) red_s[wv][ln] = v;
        }
        __syncthreads();
        if (tid < NC) {
            float sn = red_s[0][tid] + red_s[1][tid] + red_s[2][tid] + red_s[3][tid];
            sig_s[tid] = ll * sqrtf(sn) * rsqrtf(2.f * cnt[c0 + tid] * al);
        }
        __syncthreads();

        // ================= pass C: t accumulation (2 x 2-column) ==========
#pragma unroll
        for (int hf = 0; hf < 2; ++hf) {
            float sg0 = sig_s[hf * 2], sg1 = sig_s[hf * 2 + 1];
            float isg0 = 1.f / sg0, isg1 = 1.f / sg1;
            hf2 b20[8], b21[8];
#pragma unroll
            for (int q = 0; q < 8; ++q) {
                b20[q] = hf2{(_Float16)beta_s[hf * 2][2 * q],
                             (_Float16)beta_s[hf * 2][2 * q + 1]};
                b21[q] = hf2{(_Float16)beta_s[hf * 2 + 1][2 * q],
                             (_Float16)beta_s[hf * 2 + 1][2 * q + 1]};
            }
            float v[32];   // tac flattened: idx = i*16+s
#pragma unroll
            for (int j = 0; j < 32; ++j) v[j] = 0.f;
#pragma unroll 2
            for (int k = 0; k < 16; ++k) {
                int m = tid + (k << 8);
                union { uint4 w[2]; unsigned u[8]; _Float16 h[16]; } uu;
                uu.w[0] = *(const uint4*)(Dh + (size_t)m * RDIM);
                uu.w[1] = *(const uint4*)(Dh + (size_t)m * RDIM + 8);
                {   // column hf*2
                    float xv = __half2float(Xcol[(hf * 2) * DIM + m]);
                    float dot = dot16(uu.u, b20);
                    float res = (xv != 0.f) ? (xv - dot) : 0.f;
                    float psi2 = fminf(fmaxf(res * isg0, -cl), cl);
                    float coeff = psi2 * sg0;
#pragma unroll
                    for (int s = 0; s < 16; ++s)
                        v[s] = fmaf((float)uu.h[s], coeff, v[s]);   // v_fma_mix
                }
                {   // column hf*2+1
                    float xv = __half2float(Xcol[(hf * 2 + 1) * DIM + m]);
                    float dot = dot16(uu.u, b21);
                    float res = (xv != 0.f) ? (xv - dot) : 0.f;
                    float psi2 = fminf(fmaxf(res * isg1, -cl), cl);
                    float coeff = psi2 * sg1;
#pragma unroll
                    for (int s = 0; s < 16; ++s)
                        v[16 + s] = fmaf((float)uu.h[s], coeff, v[16 + s]);
                }
            }
            // wave tree-reduce 32 values -> lane (ln&31); value selects, no
            // runtime array indexing (rule #20).
#pragma unroll
            for (int b = 4; b >= 0; --b) {
                const int half = 1 << b;
                int hi = (ln >> b) & 1;
#pragma unroll
                for (int j = 0; j < half; ++j) {
                    float lo_v = v[j], hi_v = v[j + half];
                    float keep = hi ? hi_v : lo_v;
                    float send = hi ? lo_v : hi_v;
                    v[j] = keep + __shfl_xor(send, half, 64);
                }
            }
            float tv = v[0] + __shfl_xor(v[0], 32, 64);
            if (ln < 32) red_s[wv][hf * 32 + ln] = tv;
        }
        __syncthreads();

        // ================= update: beta += mu * Ainv t =====================
        if (tid < 64)
            t_sh[tid >> 4][tid & 15] = red_s[0][tid] + red_s[1][tid] +
                                       red_s[2][tid] + red_s[3][tid];
        __syncthreads();
        if (tid < 64) {
            int c = tid >> 4, j = tid & 15;
            float d = 0.f;
#pragma unroll
            for (int q = 0; q < 4; ++q) {
                float4 a4 = *(float4*)&ainv_s[c][j][q * 4];
                d += a4.x * t_sh[c][q * 4 + 0] + a4.y * t_sh[c][q * 4 + 1] +
                     a4.z * t_sh[c][q * 4 + 2] + a4.w * t_sh[c][q * 4 + 3];
            }
            beta_s[c][j] += ml * d;
        }
        __syncthreads();
    }

    // ================= epilogue ===========================================
    if (tid < NC * 16) {
        int c = tid >> 4, j = tid & 15;
        float bv = beta_s[c][j];
        B[(size_t)(c0 + c) * RDIM + j] = bv;
        Bh[(size_t)(c0 + c) * RDIM + j] = __float2half(bv);
    }
    if (do_pt && tid >= 112 && tid < 256) {
        int rs = tid - 112;
        int rr = 16, ss = 0;
#pragma unroll
        for (int r = 0; r < 16; ++r) {
            int base = r * (31 - r) / 2;
            if (rs >= base + r && rs <= base + 15) { rr = r; ss = rs - base; }
        }
#pragma unroll
        for (int c = 0; c < NC; ++c) {
            float p = (rr < 16) ? beta_s[c][rr] * beta_s[c][ss] : 0.f;
            Pt[(size_t)rs * DIM + c0 + c] = bf16_rne(p);
        }
    }
}

// ---------------- final out = Uc @ Vtb^T -----------------------------------
__global__ void __launch_bounds__(256) k_out(const float* __restrict__ Uc,
                                             const float* __restrict__ Vtb,
                                             float* __restrict__ out) {
    __shared__ float us[64 * RDIM];
    int j = blockIdx.x * 256 + threadIdx.x;
    int i0 = blockIdx.y * 64;
    ((float4*)us)[threadIdx.x] = ((const float4*)(Uc + (size_t)i0 * RDIM))[threadIdx.x];
    float beta[16];
#pragma unroll
    for (int q = 0; q < 4; ++q) {
        float4 t4 = ((const float4*)(Vtb + (size_t)j * RDIM))[q];
        beta[q * 4 + 0] = t4.x; beta[q * 4 + 1] = t4.y;
        beta[q * 4 + 2] = t4.z; beta[q * 4 + 3] = t4.w;
    }
    __syncthreads();
#pragma unroll 4
    for (int r = 0; r < 64; ++r) {
        float dot = 0.f;
#pragma unroll
        for (int q = 0; q < 4; ++q) {
            float4 u4 = *(const float4*)(us + r * RDIM + q * 4);
            dot += u4.x * beta[q * 4 + 0] + u4.y * beta[q * 4 + 1] +
                   u4.z * beta[q * 4 + 2] + u4.w * beta[q * 4 + 3];
        }
        out[(size_t)(i0 + r) * DIM + j] = dot;
    }
}

extern "C" void kernel_launch(void* const* d_in, const int* in_sizes, int n_in,
                              void* d_out, int out_size, void* d_ws, size_t ws_size,
                              hipStream_t stream) {
    const float* U = (const float*)d_in[0];
    const float* V = (const float*)d_in[1];
    const float* X = (const float*)d_in[2];
    const float* cvec = (const float*)d_in[3];
    const float* lvec = (const float*)d_in[4];
    const float* mvec = (const float*)d_in[5];
    const float* sigma = (const float*)d_in[6];
    float* out = (float*)d_out;

    float* ws = (float*)d_ws;
    float* Apad = ws;                                   // KCH*DIM*NPKP = 4.72M f
    float* cntc = Apad + (size_t)KCH * DIM * NPKP;      // DIM
    float* cntr = cntc + DIM;                           // DIM
    float* Uc   = cntr + DIM;                           // DIM*16
    float* Vtb  = Uc + (size_t)DIM * RDIM;              // DIM*16
    __half* Uch  = (__half*)(Vtb + (size_t)DIM * RDIM); // DIM*16 halves
    __half* Vtbh = Uch + (size_t)DIM * RDIM;            // DIM*16 halves
    unsigned short* Pt = (unsigned short*)(Vtbh + (size_t)DIM * RDIM); // 144*DIM u16
    // fp16 X copies live in d_out (scratch until k_out): exactly fills out_size.
    __half* Xh  = (__half*)out;
    __half* XhT = Xh + (size_t)DIM * DIM;

    hipMemsetAsync(cntc, 0, (size_t)2 * DIM * sizeof(float), stream);

    k_transpose<<<dim3(64, 64), 256, 0, stream>>>(X, Xh, XhT, cntc, cntr);
    k_init_uc<<<64, 256, 0, stream>>>(U, Uc, Uch);
    k_init_vt<<<16, 256, 0, stream>>>(V, Vtb);
    k_prep<<<dim3(16, NPKP), 256, 0, stream>>>(Uc, Pt);

    for (int layer = 0; layer < 3; ++layer) {
        int last = (layer == 2);
        // ---- V step: design Uc/Uch; solved entities = columns of X, which
        //      are contiguous rows of XhT (both buildA and hub read XhT) ----
        k_buildA<<<512, 256, 0, stream>>>(XhT, Pt, Apad);
        k_hub<<<1024, 256, 0, stream>>>(XhT, Uch, Apad, sigma, cntc,
                                        cvec, lvec, mvec, layer,
                                        Vtb, Vtbh, Pt, 1);
        // ---- U step: design Vtb/Vtbh; solved entities = rows of X ----
        k_buildA<<<512, 256, 0, stream>>>(Xh, Pt, Apad);
        k_hub<<<1024, 256, 0, stream>>>(Xh, Vtbh, Apad, sigma, cntr,
                                        cvec, lvec, mvec, layer,
                                        Uc, Uch, last ? nullptr : Pt, last ? 0 : 1);
    }
    k_out<<<dim3(16, 64), 256, 0, stream>>>(Uc, Vtb, out);
}